// Round 1
// baseline (4085.754 us; speedup 1.0000x reference)
//
#include <hip/hip_runtime.h>
#include <cstddef>

#define NN 40000
#define NE 400000
#define NG 128

// ---------------- fp32 tiled GEMM: C[M,N] = A[M,K] @ B[K,N] ----------------
// 128x128 tile, BK=8, 256 threads, 8x8 micro-tile per thread.
__global__ __launch_bounds__(256) void gemm_f32(
    const float* __restrict__ A, const float* __restrict__ B,
    float* __restrict__ C, int M, int K, int N)
{
    __shared__ float As[8][132];
    __shared__ float Bs[8][128];
    const int bm = blockIdx.x * 128;
    const int bn = blockIdx.y * 128;
    const int t  = threadIdx.x;
    const int tm = t >> 4;          // 0..15
    const int tn = t & 15;          // 0..15
    const int ar = t >> 1;          // 0..127 (tile row for A load)
    const int ak = (t & 1) * 4;     // 0 or 4
    const int bk = t >> 5;          // 0..7
    const int bn4 = (t & 31) * 4;   // 0..124

    float acc[8][8] = {};
    const int arow = bm + ar;
    const float* Aptr = A + (size_t)arow * K + ak;

    for (int kt = 0; kt < K; kt += 8) {
        float4 av = make_float4(0.f, 0.f, 0.f, 0.f);
        if (arow < M) av = *(const float4*)(Aptr + kt);
        As[ak + 0][ar] = av.x;
        As[ak + 1][ar] = av.y;
        As[ak + 2][ar] = av.z;
        As[ak + 3][ar] = av.w;
        *(float4*)&Bs[bk][bn4] = *(const float4*)&B[(size_t)(kt + bk) * N + bn + bn4];
        __syncthreads();
        #pragma unroll
        for (int k = 0; k < 8; ++k) {
            float a[8], b[8];
            #pragma unroll
            for (int i = 0; i < 8; ++i) a[i] = As[k][tm * 8 + i];
            #pragma unroll
            for (int j = 0; j < 8; ++j) b[j] = Bs[k][tn * 8 + j];
            #pragma unroll
            for (int i = 0; i < 8; ++i)
                #pragma unroll
                for (int j = 0; j < 8; ++j)
                    acc[i][j] = fmaf(a[i], b[j], acc[i][j]);
        }
        __syncthreads();
    }
    #pragma unroll
    for (int i = 0; i < 8; ++i) {
        int row = bm + tm * 8 + i;
        if (row < M) {
            float* cp = C + (size_t)row * N + bn + tn * 8;
            *(float4*)cp       = make_float4(acc[i][0], acc[i][1], acc[i][2], acc[i][3]);
            *(float4*)(cp + 4) = make_float4(acc[i][4], acc[i][5], acc[i][6], acc[i][7]);
        }
    }
}

// ------------- el/er: per (node, head) dot(feat[n,h,:], a[h,:]) -------------
template <int H>
__global__ __launch_bounds__(256) void eler_kernel(
    const float* __restrict__ feat, const float* __restrict__ al,
    const float* __restrict__ ar, float* __restrict__ el, float* __restrict__ er)
{
    int wid  = (blockIdx.x * 256 + threadIdx.x) >> 6;
    int lane = threadIdx.x & 63;
    if (wid >= NN * H) return;
    int n = wid / H, h = wid % H;
    const float* f = feat + (size_t)n * (H * 128) + h * 128;
    float2 fv = *(const float2*)&f[lane * 2];
    float2 a1 = *(const float2*)&al[h * 128 + lane * 2];
    float2 a2 = *(const float2*)&ar[h * 128 + lane * 2];
    float sl = fv.x * a1.x + fv.y * a1.y;
    float sr = fv.x * a2.x + fv.y * a2.y;
    #pragma unroll
    for (int off = 32; off > 0; off >>= 1) {
        sl += __shfl_down(sl, off);
        sr += __shfl_down(sr, off);
    }
    if (lane == 0) { el[wid] = sl; er[wid] = sr; }
}

// -------- per-edge attention weight w = exp(leakyrelu(el[s]+er[d])) --------
template <int H>
__global__ __launch_bounds__(256) void edge_w_kernel(
    const int* __restrict__ src, const int* __restrict__ dst,
    const float* __restrict__ el, const float* __restrict__ er,
    float* __restrict__ w, float* __restrict__ den)
{
    int e = blockIdx.x * 256 + threadIdx.x;
    if (e >= NE) return;
    int s = src[e], d = dst[e];
    if constexpr (H == 4) {
        float4 a = *(const float4*)&el[s * 4];
        float4 b = *(const float4*)&er[d * 4];
        float4 v = make_float4(a.x + b.x, a.y + b.y, a.z + b.z, a.w + b.w);
        v.x = v.x > 0.f ? v.x : 0.2f * v.x;
        v.y = v.y > 0.f ? v.y : 0.2f * v.y;
        v.z = v.z > 0.f ? v.z : 0.2f * v.z;
        v.w = v.w > 0.f ? v.w : 0.2f * v.w;
        float4 wv = make_float4(__expf(v.x), __expf(v.y), __expf(v.z), __expf(v.w));
        *(float4*)&w[e * 4] = wv;
        unsafeAtomicAdd(&den[d * 4 + 0], wv.x);
        unsafeAtomicAdd(&den[d * 4 + 1], wv.y);
        unsafeAtomicAdd(&den[d * 4 + 2], wv.z);
        unsafeAtomicAdd(&den[d * 4 + 3], wv.w);
    } else {
        float v = el[s] + er[d];
        v = v > 0.f ? v : 0.2f * v;
        float wv = __expf(v);
        w[e] = wv;
        unsafeAtomicAdd(&den[d], wv);
    }
}

// ---- per-edge weighted scatter: out[dst] += alpha * feat[src] (1 wave/edge) ----
template <int H>
__global__ __launch_bounds__(256) void scatter_kernel(
    const int* __restrict__ src, const int* __restrict__ dst,
    const float* __restrict__ feat, const float* __restrict__ w,
    const float* __restrict__ den, float* __restrict__ out)
{
    int wave = (blockIdx.x * 256 + threadIdx.x) >> 6;
    int lane = threadIdx.x & 63;
    if (wave >= NE) return;
    int s = src[wave], d = dst[wave];
    if constexpr (H == 4) {
        float a0 = w[wave * 4 + 0] / den[d * 4 + 0];
        float a1 = w[wave * 4 + 1] / den[d * 4 + 1];
        float a2 = w[wave * 4 + 2] / den[d * 4 + 2];
        float a3 = w[wave * 4 + 3] / den[d * 4 + 3];
        const float* f = feat + (size_t)s * 512;
        float* o = out + (size_t)d * 512;
        {
            int idx = lane * 4;
            float4 v = *(const float4*)&f[idx];
            float a = (lane & 32) ? a1 : a0;
            unsafeAtomicAdd(&o[idx + 0], v.x * a);
            unsafeAtomicAdd(&o[idx + 1], v.y * a);
            unsafeAtomicAdd(&o[idx + 2], v.z * a);
            unsafeAtomicAdd(&o[idx + 3], v.w * a);
        }
        {
            int idx = 256 + lane * 4;
            float4 v = *(const float4*)&f[idx];
            float a = (lane & 32) ? a3 : a2;
            unsafeAtomicAdd(&o[idx + 0], v.x * a);
            unsafeAtomicAdd(&o[idx + 1], v.y * a);
            unsafeAtomicAdd(&o[idx + 2], v.z * a);
            unsafeAtomicAdd(&o[idx + 3], v.w * a);
        }
    } else {
        float alpha = w[wave] / den[d];
        const float* f = feat + (size_t)s * 128;
        float* o = out + (size_t)d * 128;
        int idx = lane * 2;
        float2 v = *(const float2*)&f[idx];
        unsafeAtomicAdd(&o[idx + 0], v.x * alpha);
        unsafeAtomicAdd(&o[idx + 1], v.y * alpha);
    }
}

// --------- broadcast-init: out[i] = bias[i & mask] (bias into h buffers) ---------
__global__ void init_bias_kernel(float* __restrict__ out, const float* __restrict__ bias,
                                 size_t total, int mask)
{
    size_t i = (size_t)blockIdx.x * 256 + threadIdx.x;
    if (i < total) out[i] = bias[i & mask];
}

__global__ void graph_count_kernel(const int* __restrict__ gid, int* __restrict__ cnt)
{
    int n = blockIdx.x * 256 + threadIdx.x;
    if (n < NN) atomicAdd(&cnt[gid[n]], 1);
}

__global__ __launch_bounds__(256) void graph_sum_kernel(
    const int* __restrict__ gid, const float* __restrict__ h2, float* __restrict__ hg)
{
    int wave = (blockIdx.x * 256 + threadIdx.x) >> 6;
    int lane = threadIdx.x & 63;
    if (wave >= NN) return;
    int g = gid[wave];
    float2 v = *(const float2*)&h2[(size_t)wave * 128 + lane * 2];
    unsafeAtomicAdd(&hg[g * 128 + lane * 2 + 0], v.x);
    unsafeAtomicAdd(&hg[g * 128 + lane * 2 + 1], v.y);
}

// --------- node MLP: out = relu(h @ W1 + b1) @ W2 + b2 (one node/block) ---------
__global__ __launch_bounds__(128) void node_mlp_kernel(
    const float* __restrict__ h, const float* __restrict__ W1,
    const float* __restrict__ b1, const float* __restrict__ W2,
    const float* __restrict__ b2, float* __restrict__ out)
{
    __shared__ float row[128];
    __shared__ float hid[128];
    int n = blockIdx.x;
    int t = threadIdx.x;
    row[t] = h[(size_t)n * 128 + t];
    __syncthreads();
    float acc = b1[t];
    #pragma unroll 8
    for (int k = 0; k < 128; ++k) acc = fmaf(row[k], W1[k * 128 + t], acc);
    hid[t] = fmaxf(acc, 0.f);
    __syncthreads();
    if (t < 2) {
        float o = b2[t];
        for (int k = 0; k < 128; ++k) o = fmaf(hid[k], W2[k * 2 + t], o);
        out[(size_t)n * 2 + t] = o;
    }
}

__global__ __launch_bounds__(128) void graph_mlp_kernel(
    const float* __restrict__ hg, const int* __restrict__ cnt,
    const float* __restrict__ W1, const float* __restrict__ b1,
    const float* __restrict__ W2, const float* __restrict__ b2,
    float* __restrict__ out)
{
    __shared__ float row[128];
    __shared__ float hid[128];
    int g = blockIdx.x;
    int t = threadIdx.x;
    float c = fmaxf((float)cnt[g], 1.0f);
    row[t] = hg[(size_t)g * 128 + t] / c;
    __syncthreads();
    float acc = b1[t];
    #pragma unroll 8
    for (int k = 0; k < 128; ++k) acc = fmaf(row[k], W1[k * 128 + t], acc);
    hid[t] = fmaxf(acc, 0.f);
    __syncthreads();
    if (t < 2) {
        float o = b2[t];
        for (int k = 0; k < 128; ++k) o = fmaf(hid[k], W2[k * 2 + t], o);
        out[(size_t)g * 2 + t] = o;
    }
}

// ---------------------------------------------------------------------------
// workspace layout (float offsets). feat2/h2 alias the dead feat1 region.
static constexpr size_t O_FEAT1 = 0;          // 40000*512
static constexpr size_t O_H1    = 20480000;   // 40000*512
static constexpr size_t O_FEAT2 = 0;          // 40000*128 (alias)
static constexpr size_t O_H2    = 5120000;    // 40000*128 (alias)
static constexpr size_t O_EL1   = 40960000;   // 160000
static constexpr size_t O_ER1   = 41120000;   // 160000
static constexpr size_t O_W1E   = 41280000;   // 1600000
static constexpr size_t O_EL2   = 42880000;   // 40000
static constexpr size_t O_ER2   = 42920000;   // 40000
static constexpr size_t O_W2E   = 42960000;   // 400000
static constexpr size_t O_DEN1  = 43360000;   // 160000
static constexpr size_t O_DEN2  = 43520000;   // 40000
static constexpr size_t O_HG    = 43560000;   // 16384
static constexpr size_t O_CNT   = 43576384;   // 128 ints
static constexpr size_t ZERO_FLOATS = 160000 + 40000 + 16384 + 128;

extern "C" void kernel_launch(void* const* d_in, const int* in_sizes, int n_in,
                              void* d_out, int out_size, void* d_ws, size_t ws_size,
                              hipStream_t stream)
{
    const float* x    = (const float*)d_in[0];
    const int*   src  = (const int*)d_in[1];
    const int*   dst  = (const int*)d_in[2];
    const int*   gid  = (const int*)d_in[3];
    const float* W1   = (const float*)d_in[4];
    const float* al1  = (const float*)d_in[5];
    const float* ar1  = (const float*)d_in[6];
    const float* b1   = (const float*)d_in[7];
    const float* W2   = (const float*)d_in[8];
    const float* al2  = (const float*)d_in[9];
    const float* ar2  = (const float*)d_in[10];
    const float* b2   = (const float*)d_in[11];
    const float* nW1  = (const float*)d_in[12];
    const float* nb1  = (const float*)d_in[13];
    const float* nW2  = (const float*)d_in[14];
    const float* nb2  = (const float*)d_in[15];
    const float* gW1  = (const float*)d_in[16];
    const float* gb1  = (const float*)d_in[17];
    const float* gW2  = (const float*)d_in[18];
    const float* gb2  = (const float*)d_in[19];
    float* out = (float*)d_out;
    float* ws  = (float*)d_ws;

    float* feat1 = ws + O_FEAT1;
    float* h1    = ws + O_H1;
    float* feat2 = ws + O_FEAT2;
    float* h2    = ws + O_H2;
    float* el1   = ws + O_EL1;
    float* er1   = ws + O_ER1;
    float* w1e   = ws + O_W1E;
    float* el2   = ws + O_EL2;
    float* er2   = ws + O_ER2;
    float* w2e   = ws + O_W2E;
    float* den1  = ws + O_DEN1;
    float* den2  = ws + O_DEN2;
    float* hg    = ws + O_HG;
    int*   cnt   = (int*)(ws + O_CNT);

    // zero: den1, den2, hg, cnt (contiguous)
    hipMemsetAsync(ws + O_DEN1, 0, ZERO_FLOATS * sizeof(float), stream);

    // ---- GAT layer 1 (768 -> 4x128) ----
    gemm_f32<<<dim3(313, 4), 256, 0, stream>>>(x, W1, feat1, NN, 768, 512);
    eler_kernel<4><<<40000, 256, 0, stream>>>(feat1, al1, ar1, el1, er1);
    edge_w_kernel<4><<<(NE + 255) / 256, 256, 0, stream>>>(src, dst, el1, er1, w1e, den1);
    init_bias_kernel<<<80000, 256, 0, stream>>>(h1, b1, (size_t)NN * 512, 511);
    scatter_kernel<4><<<100000, 256, 0, stream>>>(src, dst, feat1, w1e, den1, h1);

    // ---- GAT layer 2 (512 -> 1x128) ----
    gemm_f32<<<dim3(313, 1), 256, 0, stream>>>(h1, W2, feat2, NN, 512, 128);
    eler_kernel<1><<<10000, 256, 0, stream>>>(feat2, al2, ar2, el2, er2);
    edge_w_kernel<1><<<(NE + 255) / 256, 256, 0, stream>>>(src, dst, el2, er2, w2e, den2);
    init_bias_kernel<<<20000, 256, 0, stream>>>(h2, b2, (size_t)NN * 128, 127);
    scatter_kernel<1><<<100000, 256, 0, stream>>>(src, dst, feat2, w2e, den2, h2);

    // ---- pooling + MLPs ----
    graph_count_kernel<<<(NN + 255) / 256, 256, 0, stream>>>(gid, cnt);
    graph_sum_kernel<<<10000, 256, 0, stream>>>(gid, h2, hg);
    node_mlp_kernel<<<NN, 128, 0, stream>>>(h2, nW1, nb1, nW2, nb2, out);
    graph_mlp_kernel<<<NG, 128, 0, stream>>>(hg, cnt, gW1, gb1, gW2, gb2, out + (size_t)NN * 2);
}

// Round 3
// 1203.160 us; speedup vs baseline: 3.3959x; 3.3959x over previous
//
#include <hip/hip_runtime.h>
#include <cstddef>

#define NN 40000
#define NE 400000
#define NG 128
#define NB_SCAN 157  // ceil(40000/256)

// ---------------- fp32 tiled GEMM: C[M,N] = A[M,K] @ B[K,N] ----------------
__global__ __launch_bounds__(256) void gemm_f32(
    const float* __restrict__ A, const float* __restrict__ B,
    float* __restrict__ C, int M, int K, int N)
{
    __shared__ float As[8][132];
    __shared__ float Bs[8][128];
    const int bm = blockIdx.x * 128;
    const int bn = blockIdx.y * 128;
    const int t  = threadIdx.x;
    const int tm = t >> 4;
    const int tn = t & 15;
    const int ar = t >> 1;
    const int ak = (t & 1) * 4;
    const int bk = t >> 5;
    const int bn4 = (t & 31) * 4;

    float acc[8][8] = {};
    const int arow = bm + ar;
    const float* Aptr = A + (size_t)arow * K + ak;

    for (int kt = 0; kt < K; kt += 8) {
        float4 av = make_float4(0.f, 0.f, 0.f, 0.f);
        if (arow < M) av = *(const float4*)(Aptr + kt);
        As[ak + 0][ar] = av.x;
        As[ak + 1][ar] = av.y;
        As[ak + 2][ar] = av.z;
        As[ak + 3][ar] = av.w;
        *(float4*)&Bs[bk][bn4] = *(const float4*)&B[(size_t)(kt + bk) * N + bn + bn4];
        __syncthreads();
        #pragma unroll
        for (int k = 0; k < 8; ++k) {
            float a[8], b[8];
            #pragma unroll
            for (int i = 0; i < 8; ++i) a[i] = As[k][tm * 8 + i];
            #pragma unroll
            for (int j = 0; j < 8; ++j) b[j] = Bs[k][tn * 8 + j];
            #pragma unroll
            for (int i = 0; i < 8; ++i)
                #pragma unroll
                for (int j = 0; j < 8; ++j)
                    acc[i][j] = fmaf(a[i], b[j], acc[i][j]);
        }
        __syncthreads();
    }
    #pragma unroll
    for (int i = 0; i < 8; ++i) {
        int row = bm + tm * 8 + i;
        if (row < M) {
            float* cp = C + (size_t)row * N + bn + tn * 8;
            *(float4*)cp       = make_float4(acc[i][0], acc[i][1], acc[i][2], acc[i][3]);
            *(float4*)(cp + 4) = make_float4(acc[i][4], acc[i][5], acc[i][6], acc[i][7]);
        }
    }
}

// ---------------- CSR build: histogram -> scan -> permute ----------------
__global__ void hist_kernel(const int* __restrict__ dst, int* __restrict__ cnt)
{
    int e = blockIdx.x * 256 + threadIdx.x;
    if (e < NE) atomicAdd(&cnt[dst[e]], 1);
}

__global__ __launch_bounds__(256) void scanA_kernel(
    const int* __restrict__ cnt, int* __restrict__ row, int* __restrict__ bsum)
{
    __shared__ int s[256];
    int t = threadIdx.x;
    int i = blockIdx.x * 256 + t;
    int v = (i < NN) ? cnt[i] : 0;
    s[t] = v;
    __syncthreads();
    #pragma unroll
    for (int off = 1; off < 256; off <<= 1) {
        int x = (t >= off) ? s[t - off] : 0;
        __syncthreads();
        s[t] += x;
        __syncthreads();
    }
    if (i < NN) row[i] = s[t] - v;     // exclusive
    if (t == 255) bsum[blockIdx.x] = s[255];
}

__global__ __launch_bounds__(256) void scanB_kernel(int* __restrict__ bsum)
{
    __shared__ int s[256];
    int t = threadIdx.x;
    int v = (t < NB_SCAN) ? bsum[t] : 0;
    s[t] = v;
    __syncthreads();
    #pragma unroll
    for (int off = 1; off < 256; off <<= 1) {
        int x = (t >= off) ? s[t - off] : 0;
        __syncthreads();
        s[t] += x;
        __syncthreads();
    }
    if (t < NB_SCAN) bsum[t] = s[t] - v;  // exclusive
}

__global__ void scanC_kernel(int* __restrict__ row, const int* __restrict__ bsum,
                             int* __restrict__ fill)
{
    int i = blockIdx.x * 256 + threadIdx.x;
    if (i < NN) {
        int r = row[i] + bsum[blockIdx.x];
        row[i] = r;
        fill[i] = r;
    }
    if (i == 0) row[NN] = NE;
}

__global__ void permute_kernel(const int* __restrict__ dst, int* __restrict__ fill,
                               int* __restrict__ eidx)
{
    int e = blockIdx.x * 256 + threadIdx.x;
    if (e < NE) {
        int pos = atomicAdd(&fill[dst[e]], 1);
        eidx[pos] = e;
    }
}

// ------------- el/er: per (node, head) dot(feat[n,h,:], a[h,:]) -------------
template <int H>
__global__ __launch_bounds__(256) void eler_kernel(
    const float* __restrict__ feat, const float* __restrict__ al,
    const float* __restrict__ ar, float* __restrict__ el, float* __restrict__ er)
{
    int wid  = (blockIdx.x * 256 + threadIdx.x) >> 6;
    int lane = threadIdx.x & 63;
    if (wid >= NN * H) return;
    int n = wid / H, h = wid % H;
    const float* f = feat + (size_t)n * (H * 128) + h * 128;
    float2 fv = *(const float2*)&f[lane * 2];
    float2 a1 = *(const float2*)&al[h * 128 + lane * 2];
    float2 a2 = *(const float2*)&ar[h * 128 + lane * 2];
    float sl = fv.x * a1.x + fv.y * a1.y;
    float sr = fv.x * a2.x + fv.y * a2.y;
    #pragma unroll
    for (int off = 32; off > 0; off >>= 1) {
        sl += __shfl_down(sl, off);
        sr += __shfl_down(sr, off);
    }
    if (lane == 0) { el[wid] = sl; er[wid] = sr; }
}

// -------- per-edge attention weight w = exp(leakyrelu(el[s]+er[d])) --------
template <int H>
__global__ __launch_bounds__(256) void edge_w_kernel(
    const int* __restrict__ src, const int* __restrict__ dst,
    const float* __restrict__ el, const float* __restrict__ er,
    float* __restrict__ w)
{
    int e = blockIdx.x * 256 + threadIdx.x;
    if (e >= NE) return;
    int s = src[e], d = dst[e];
    if constexpr (H == 4) {
        float4 a = *(const float4*)&el[s * 4];
        float4 b = *(const float4*)&er[d * 4];
        float4 v = make_float4(a.x + b.x, a.y + b.y, a.z + b.z, a.w + b.w);
        v.x = v.x > 0.f ? v.x : 0.2f * v.x;
        v.y = v.y > 0.f ? v.y : 0.2f * v.y;
        v.z = v.z > 0.f ? v.z : 0.2f * v.z;
        v.w = v.w > 0.f ? v.w : 0.2f * v.w;
        *(float4*)&w[e * 4] = make_float4(__expf(v.x), __expf(v.y), __expf(v.z), __expf(v.w));
    } else {
        float v = el[s] + er[d];
        v = v > 0.f ? v : 0.2f * v;
        w[e] = __expf(v);
    }
}

// ---- CSR gather-aggregate: one wave per dst node, registers only, bias folded ----
template <int H>
__global__ __launch_bounds__(256) void agg_kernel(
    const int* __restrict__ row, const int* __restrict__ eidx,
    const int* __restrict__ src, const float* __restrict__ w,
    const float* __restrict__ feat, const float* __restrict__ bias,
    float* __restrict__ out)
{
    int wave = (blockIdx.x * 256 + threadIdx.x) >> 6;
    int lane = threadIdx.x & 63;
    if (wave >= NN) return;
    int r0 = row[wave], r1 = row[wave + 1];

    if constexpr (H == 4) {
        float d0 = 0.f, d1 = 0.f, d2 = 0.f, d3 = 0.f;
        for (int i = r0 + lane; i < r1; i += 64) {
            float4 wv = *(const float4*)&w[eidx[i] * 4];
            d0 += wv.x; d1 += wv.y; d2 += wv.z; d3 += wv.w;
        }
        #pragma unroll
        for (int off = 32; off > 0; off >>= 1) {
            d0 += __shfl_xor(d0, off);
            d1 += __shfl_xor(d1, off);
            d2 += __shfl_xor(d2, off);
            d3 += __shfl_xor(d3, off);
        }
        float4 a0 = {0.f,0.f,0.f,0.f}, a1 = {0.f,0.f,0.f,0.f};
        for (int i = r0; i < r1; ++i) {
            int e = eidx[i];
            int s = src[e];
            float4 wv = *(const float4*)&w[e * 4];
            const float* f = feat + (size_t)s * 512;
            float4 v0 = *(const float4*)&f[lane * 4];
            float4 v1 = *(const float4*)&f[256 + lane * 4];
            float alo = (lane & 32) ? wv.y : wv.x;
            float ahi = (lane & 32) ? wv.w : wv.z;
            a0.x = fmaf(v0.x, alo, a0.x); a0.y = fmaf(v0.y, alo, a0.y);
            a0.z = fmaf(v0.z, alo, a0.z); a0.w = fmaf(v0.w, alo, a0.w);
            a1.x = fmaf(v1.x, ahi, a1.x); a1.y = fmaf(v1.y, ahi, a1.y);
            a1.z = fmaf(v1.z, ahi, a1.z); a1.w = fmaf(v1.w, ahi, a1.w);
        }
        float ilo = (lane & 32) ? d1 : d0;
        float ihi = (lane & 32) ? d3 : d2;
        ilo = (r1 > r0) ? 1.0f / ilo : 0.0f;
        ihi = (r1 > r0) ? 1.0f / ihi : 0.0f;
        float4 b0 = *(const float4*)&bias[lane * 4];
        float4 b1v = *(const float4*)&bias[256 + lane * 4];
        float* o = out + (size_t)wave * 512;
        *(float4*)&o[lane * 4] = make_float4(
            fmaf(a0.x, ilo, b0.x), fmaf(a0.y, ilo, b0.y),
            fmaf(a0.z, ilo, b0.z), fmaf(a0.w, ilo, b0.w));
        *(float4*)&o[256 + lane * 4] = make_float4(
            fmaf(a1.x, ihi, b1v.x), fmaf(a1.y, ihi, b1v.y),
            fmaf(a1.z, ihi, b1v.z), fmaf(a1.w, ihi, b1v.w));
    } else {
        float den = 0.f;
        for (int i = r0 + lane; i < r1; i += 64) den += w[eidx[i]];
        #pragma unroll
        for (int off = 32; off > 0; off >>= 1) den += __shfl_xor(den, off);
        float2 a = {0.f, 0.f};
        for (int i = r0; i < r1; ++i) {
            int e = eidx[i];
            int s = src[e];
            float wv = w[e];
            float2 v = *(const float2*)&feat[(size_t)s * 128 + lane * 2];
            a.x = fmaf(v.x, wv, a.x);
            a.y = fmaf(v.y, wv, a.y);
        }
        float inv = (r1 > r0) ? 1.0f / den : 0.0f;
        float2 b = *(const float2*)&bias[lane * 2];
        float* o = out + (size_t)wave * 128;
        *(float2*)&o[lane * 2] = make_float2(fmaf(a.x, inv, b.x), fmaf(a.y, inv, b.y));
    }
}

// --------- per-graph mean via binary search on sorted graph_ids ---------
__global__ __launch_bounds__(128) void graph_mean_kernel(
    const int* __restrict__ gid, const float* __restrict__ h2, float* __restrict__ hg)
{
    int g = blockIdx.x;
    int t = threadIdx.x;
    // lower_bound(gid, g) and lower_bound(gid, g+1)
    int lo = 0, hi = NN;
    while (lo < hi) { int m = (lo + hi) >> 1; if (gid[m] < g) lo = m + 1; else hi = m; }
    int start = lo;
    lo = start; hi = NN;
    while (lo < hi) { int m = (lo + hi) >> 1; if (gid[m] < g + 1) lo = m + 1; else hi = m; }
    int end = lo;
    float acc = 0.f;
    for (int n = start; n < end; ++n) acc += h2[(size_t)n * 128 + t];
    float c = fmaxf((float)(end - start), 1.0f);
    hg[g * 128 + t] = acc / c;
}

// --------- node MLP: out = relu(h @ W1 + b1) @ W2 + b2 (one node/block) ---------
__global__ __launch_bounds__(128) void node_mlp_kernel(
    const float* __restrict__ h, const float* __restrict__ W1,
    const float* __restrict__ b1, const float* __restrict__ W2,
    const float* __restrict__ b2, float* __restrict__ out)
{
    __shared__ float row[128];
    __shared__ float hid[128];
    int n = blockIdx.x;
    int t = threadIdx.x;
    row[t] = h[(size_t)n * 128 + t];
    __syncthreads();
    float acc = b1[t];
    #pragma unroll 8
    for (int k = 0; k < 128; ++k) acc = fmaf(row[k], W1[k * 128 + t], acc);
    hid[t] = fmaxf(acc, 0.f);
    __syncthreads();
    if (t < 2) {
        float o = b2[t];
        for (int k = 0; k < 128; ++k) o = fmaf(hid[k], W2[k * 2 + t], o);
        out[(size_t)n * 2 + t] = o;
    }
}

__global__ __launch_bounds__(128) void graph_mlp_kernel(
    const float* __restrict__ hg,
    const float* __restrict__ W1, const float* __restrict__ b1,
    const float* __restrict__ W2, const float* __restrict__ b2,
    float* __restrict__ out)
{
    __shared__ float row[128];
    __shared__ float hid[128];
    int g = blockIdx.x;
    int t = threadIdx.x;
    row[t] = hg[(size_t)g * 128 + t];
    __syncthreads();
    float acc = b1[t];
    #pragma unroll 8
    for (int k = 0; k < 128; ++k) acc = fmaf(row[k], W1[k * 128 + t], acc);
    hid[t] = fmaxf(acc, 0.f);
    __syncthreads();
    if (t < 2) {
        float o = b2[t];
        for (int k = 0; k < 128; ++k) o = fmaf(hid[k], W2[k * 2 + t], o);
        out[(size_t)g * 2 + t] = o;
    }
}

// ---------------------------------------------------------------------------
// workspace layout (float offsets)
static constexpr size_t O_FEAT1 = 0;          // 40000*512 (layer2: feat2 @0, h2 @5120000)
static constexpr size_t O_H1    = 20480000;   // 40000*512
static constexpr size_t O_H2    = 5120000;    // alias inside feat1 region
static constexpr size_t O_EW    = 40960000;   // per-layer attn scratch (1.92M floats)
static constexpr size_t O_HG    = 42880000;   // 16384
static constexpr size_t O_INT   = 42896384;   // int region start
// int offsets within O_INT:
static constexpr size_t I_ROW  = 0;        // 40001
static constexpr size_t I_BSUM = 40064;    // 160
static constexpr size_t I_CNT  = 40224;    // 40000
static constexpr size_t I_FILL = 80224;    // 40000
static constexpr size_t I_EIDX = 120224;   // 400000

extern "C" void kernel_launch(void* const* d_in, const int* in_sizes, int n_in,
                              void* d_out, int out_size, void* d_ws, size_t ws_size,
                              hipStream_t stream)
{
    const float* x    = (const float*)d_in[0];
    const int*   src  = (const int*)d_in[1];
    const int*   dst  = (const int*)d_in[2];
    const int*   gid  = (const int*)d_in[3];
    const float* W1   = (const float*)d_in[4];
    const float* al1  = (const float*)d_in[5];
    const float* ar1  = (const float*)d_in[6];
    const float* b1   = (const float*)d_in[7];
    const float* W2   = (const float*)d_in[8];
    const float* al2  = (const float*)d_in[9];
    const float* ar2  = (const float*)d_in[10];
    const float* b2   = (const float*)d_in[11];
    const float* nW1  = (const float*)d_in[12];
    const float* nb1  = (const float*)d_in[13];
    const float* nW2  = (const float*)d_in[14];
    const float* nb2  = (const float*)d_in[15];
    const float* gW1  = (const float*)d_in[16];
    const float* gb1  = (const float*)d_in[17];
    const float* gW2  = (const float*)d_in[18];
    const float* gb2  = (const float*)d_in[19];
    float* out = (float*)d_out;
    float* ws  = (float*)d_ws;

    float* feat1 = ws + O_FEAT1;
    float* h1    = ws + O_H1;
    float* feat2 = ws + O_FEAT1;   // alias (feat1 dead after agg<4>)
    float* h2    = ws + O_H2;
    float* el1   = ws + O_EW;
    float* er1   = ws + O_EW + 160000;
    float* w1e   = ws + O_EW + 320000;
    float* el2   = ws + O_EW;      // alias (layer-1 attn scratch dead)
    float* er2   = ws + O_EW + 40000;
    float* w2e   = ws + O_EW + 80000;
    float* hg    = ws + O_HG;
    int*   ibase = (int*)(ws + O_INT);
    int*   row   = ibase + I_ROW;
    int*   bsum  = ibase + I_BSUM;
    int*   cnt   = ibase + I_CNT;
    int*   fill  = ibase + I_FILL;
    int*   eidx  = ibase + I_EIDX;

    // ---- CSR build (depends only on dst) ----
    hipMemsetAsync(cnt, 0, NN * sizeof(int), stream);
    hist_kernel<<<(NE + 255) / 256, 256, 0, stream>>>(dst, cnt);
    scanA_kernel<<<NB_SCAN, 256, 0, stream>>>(cnt, row, bsum);
    scanB_kernel<<<1, 256, 0, stream>>>(bsum);
    scanC_kernel<<<NB_SCAN, 256, 0, stream>>>(row, bsum, fill);
    permute_kernel<<<(NE + 255) / 256, 256, 0, stream>>>(dst, fill, eidx);

    // ---- GAT layer 1 (768 -> 4x128) ----
    gemm_f32<<<dim3(313, 4), 256, 0, stream>>>(x, W1, feat1, NN, 768, 512);
    eler_kernel<4><<<(NN * 4 * 64 + 255) / 256, 256, 0, stream>>>(feat1, al1, ar1, el1, er1);
    edge_w_kernel<4><<<(NE + 255) / 256, 256, 0, stream>>>(src, dst, el1, er1, w1e);
    agg_kernel<4><<<10000, 256, 0, stream>>>(row, eidx, src, w1e, feat1, b1, h1);

    // ---- GAT layer 2 (512 -> 1x128) ----
    gemm_f32<<<dim3(313, 1), 256, 0, stream>>>(h1, W2, feat2, NN, 512, 128);
    eler_kernel<1><<<(NN * 64 + 255) / 256, 256, 0, stream>>>(feat2, al2, ar2, el2, er2);
    edge_w_kernel<1><<<(NE + 255) / 256, 256, 0, stream>>>(src, dst, el2, er2, w2e);
    agg_kernel<1><<<10000, 256, 0, stream>>>(row, eidx, src, w2e, feat2, b2, h2);

    // ---- pooling + MLPs ----
    graph_mean_kernel<<<NG, 128, 0, stream>>>(gid, h2, hg);
    node_mlp_kernel<<<NN, 128, 0, stream>>>(h2, nW1, nb1, nW2, nb2, out);
    graph_mlp_kernel<<<NG, 128, 0, stream>>>(hg, gW1, gb1, gW2, gb2, out + (size_t)NN * 2);
}

// Round 8
// 999.629 us; speedup vs baseline: 4.0873x; 1.2036x over previous
//
#include <hip/hip_runtime.h>
#include <cstddef>

#define NN 40000
#define NE 400000
#define NG 128
#define NB_SCAN 157  // ceil(40000/256)

typedef __attribute__((ext_vector_type(8))) short bf16x8;
typedef __attribute__((ext_vector_type(4))) float f32x4;

// split fp32 x ~= hi + lo, both bf16 (RNE). |x - hi - lo| ~ 2^-17 |x|
__device__ __forceinline__ void split1(float x, unsigned short& h, unsigned short& l)
{
    unsigned u = __float_as_uint(x);
    unsigned rh = u + 0x7FFFu + ((u >> 16) & 1u);
    h = (unsigned short)(rh >> 16);
    float fh = __uint_as_float(((unsigned)h) << 16);
    float r = x - fh;
    unsigned u2 = __float_as_uint(r);
    unsigned rl = u2 + 0x7FFFu + ((u2 >> 16) & 1u);
    l = (unsigned short)(rl >> 16);
}

// ---- B[K][N] fp32 -> Bt hi/lo [N][K] bf16 (tiny, once per layer) ----
__global__ void conv_bt(const float* __restrict__ B, unsigned short* __restrict__ hi,
                        unsigned short* __restrict__ lo, int K, int N)
{
    int e = blockIdx.x * 256 + threadIdx.x;
    if (e >= K * N) return;
    int n = e / K, k = e - n * K;
    unsigned short h, l;
    split1(B[(size_t)k * N + n], h, l);
    hi[e] = h; lo[e] = l;
}

// ---------- split-bf16 MFMA GEMM: C[M,N] = A[M,K] @ B[K,N] (fp32 io) ----------
// 128x128 tile, BK=32, 4 waves (2x2 of 64x64), 16x16x32 bf16 MFMA, 3-product split.
#define LDK 40  // padded k-stride (bf16 elems): 80B rows -> conflict-free b128 frag reads

__global__ __launch_bounds__(256) void gemm_split(
    const float* __restrict__ A, const unsigned short* __restrict__ Bh,
    const unsigned short* __restrict__ Bl, float* __restrict__ C,
    int M, int K, int N)
{
    __shared__ unsigned short Ah_s[128 * LDK];
    __shared__ unsigned short Al_s[128 * LDK];
    __shared__ unsigned short Bh_s[128 * LDK];
    __shared__ unsigned short Bl_s[128 * LDK];

    const int t    = threadIdx.x;
    const int lane = t & 63;
    const int wid  = t >> 6;
    const int wr   = wid >> 1, wc = wid & 1;
    const int bm   = blockIdx.x * 128, bn = blockIdx.y * 128;

    const int sr = t >> 1;         // 0..127: tile row (A) / tile col (B)
    const int sk = (t & 1) * 16;   // 0 or 16: k-offset

    const int arow = bm + sr;
    const bool aval = (arow < M);
    const float* Ap = A + (size_t)arow * K + sk;
    const unsigned short* Bhp = Bh + (size_t)(bn + sr) * K + sk;
    const unsigned short* Blp = Bl + (size_t)(bn + sr) * K + sk;

    f32x4 acc[4][4];
    #pragma unroll
    for (int i = 0; i < 4; ++i)
        #pragma unroll
        for (int j = 0; j < 4; ++j) acc[i][j] = (f32x4){0.f, 0.f, 0.f, 0.f};

    float4 abuf[4];
    uint4 bhbuf[2], blbuf[2];
    const int NT = K / 32;

    auto load_tile = [&](int kt) {
        const int kb = kt * 32;
        if (aval) {
            #pragma unroll
            for (int q = 0; q < 4; ++q) abuf[q] = *(const float4*)(Ap + kb + q * 4);
        } else {
            #pragma unroll
            for (int q = 0; q < 4; ++q) abuf[q] = make_float4(0.f, 0.f, 0.f, 0.f);
        }
        bhbuf[0] = *(const uint4*)(Bhp + kb);
        bhbuf[1] = *(const uint4*)(Bhp + kb + 8);
        blbuf[0] = *(const uint4*)(Blp + kb);
        blbuf[1] = *(const uint4*)(Blp + kb + 8);
    };

    auto store_tile = [&]() {
        unsigned short h[16], l[16];
        #pragma unroll
        for (int q = 0; q < 4; ++q) {
            split1(abuf[q].x, h[q * 4 + 0], l[q * 4 + 0]);
            split1(abuf[q].y, h[q * 4 + 1], l[q * 4 + 1]);
            split1(abuf[q].z, h[q * 4 + 2], l[q * 4 + 2]);
            split1(abuf[q].w, h[q * 4 + 3], l[q * 4 + 3]);
        }
        *(uint4*)&Ah_s[sr * LDK + sk]     = *(uint4*)&h[0];
        *(uint4*)&Ah_s[sr * LDK + sk + 8] = *(uint4*)&h[8];
        *(uint4*)&Al_s[sr * LDK + sk]     = *(uint4*)&l[0];
        *(uint4*)&Al_s[sr * LDK + sk + 8] = *(uint4*)&l[8];
        *(uint4*)&Bh_s[sr * LDK + sk]     = bhbuf[0];
        *(uint4*)&Bh_s[sr * LDK + sk + 8] = bhbuf[1];
        *(uint4*)&Bl_s[sr * LDK + sk]     = blbuf[0];
        *(uint4*)&Bl_s[sr * LDK + sk + 8] = blbuf[1];
    };

    auto compute = [&]() {
        const int fr = lane & 15;
        const int fk = (lane >> 4) * 8;
        bf16x8 bhf[4], blf[4];
        #pragma unroll
        for (int ni = 0; ni < 4; ++ni) {
            bhf[ni] = *(bf16x8*)&Bh_s[(wc * 64 + ni * 16 + fr) * LDK + fk];
            blf[ni] = *(bf16x8*)&Bl_s[(wc * 64 + ni * 16 + fr) * LDK + fk];
        }
        #pragma unroll
        for (int mi = 0; mi < 4; ++mi) {
            bf16x8 ah = *(bf16x8*)&Ah_s[(wr * 64 + mi * 16 + fr) * LDK + fk];
            bf16x8 al = *(bf16x8*)&Al_s[(wr * 64 + mi * 16 + fr) * LDK + fk];
            #pragma unroll
            for (int ni = 0; ni < 4; ++ni) {
                acc[mi][ni] = __builtin_amdgcn_mfma_f32_16x16x32_bf16(ah, bhf[ni], acc[mi][ni], 0, 0, 0);
                acc[mi][ni] = __builtin_amdgcn_mfma_f32_16x16x32_bf16(ah, blf[ni], acc[mi][ni], 0, 0, 0);
                acc[mi][ni] = __builtin_amdgcn_mfma_f32_16x16x32_bf16(al, bhf[ni], acc[mi][ni], 0, 0, 0);
            }
        }
    };

    load_tile(0);
    store_tile();
    __syncthreads();
    for (int kt = 0;;) {
        if (kt + 1 < NT) load_tile(kt + 1);  // global->reg prefetch overlaps MFMA
        compute();
        ++kt;
        if (kt == NT) break;
        __syncthreads();   // all waves done reading LDS
        store_tile();
        __syncthreads();   // next tile ready
    }

    // C/D layout (m89): col = lane&15, row = (lane>>4)*4 + reg
    const int fr = lane & 15;
    const int fq = lane >> 4;
    #pragma unroll
    for (int mi = 0; mi < 4; ++mi) {
        int r0 = bm + wr * 64 + mi * 16 + fq * 4;
        #pragma unroll
        for (int ni = 0; ni < 4; ++ni) {
            int c = bn + wc * 64 + ni * 16 + fr;
            #pragma unroll
            for (int q = 0; q < 4; ++q) {
                int r = r0 + q;
                if (r < M) C[(size_t)r * N + c] = acc[mi][ni][q];
            }
        }
    }
}

// ---------------- CSR build: histogram -> scan -> permute ----------------
__global__ void hist_kernel(const int* __restrict__ dst, int* __restrict__ cnt)
{
    int e = blockIdx.x * 256 + threadIdx.x;
    if (e < NE) atomicAdd(&cnt[dst[e]], 1);
}

__global__ __launch_bounds__(256) void scanA_kernel(
    const int* __restrict__ cnt, int* __restrict__ row, int* __restrict__ bsum)
{
    __shared__ int s[256];
    int t = threadIdx.x;
    int i = blockIdx.x * 256 + t;
    int v = (i < NN) ? cnt[i] : 0;
    s[t] = v;
    __syncthreads();
    #pragma unroll
    for (int off = 1; off < 256; off <<= 1) {
        int x = (t >= off) ? s[t - off] : 0;
        __syncthreads();
        s[t] += x;
        __syncthreads();
    }
    if (i < NN) row[i] = s[t] - v;     // exclusive
    if (t == 255) bsum[blockIdx.x] = s[255];
}

__global__ __launch_bounds__(256) void scanB_kernel(int* __restrict__ bsum)
{
    __shared__ int s[256];
    int t = threadIdx.x;
    int v = (t < NB_SCAN) ? bsum[t] : 0;
    s[t] = v;
    __syncthreads();
    #pragma unroll
    for (int off = 1; off < 256; off <<= 1) {
        int x = (t >= off) ? s[t - off] : 0;
        __syncthreads();
        s[t] += x;
        __syncthreads();
    }
    if (t < NB_SCAN) bsum[t] = s[t] - v;  // exclusive
}

__global__ void scanC_kernel(int* __restrict__ row, const int* __restrict__ bsum,
                             int* __restrict__ fill)
{
    int i = blockIdx.x * 256 + threadIdx.x;
    if (i < NN) {
        int r = row[i] + bsum[blockIdx.x];
        row[i] = r;
        fill[i] = r;
    }
    if (i == 0) row[NN] = NE;
}

__global__ void permute_kernel(const int* __restrict__ dst, int* __restrict__ fill,
                               int* __restrict__ eidx)
{
    int e = blockIdx.x * 256 + threadIdx.x;
    if (e < NE) {
        int pos = atomicAdd(&fill[dst[e]], 1);
        eidx[pos] = e;
    }
}

// ------------- el/er: per (node, head) dot(feat[n,h,:], a[h,:]) -------------
template <int H>
__global__ __launch_bounds__(256) void eler_kernel(
    const float* __restrict__ feat, const float* __restrict__ al,
    const float* __restrict__ ar, float* __restrict__ el, float* __restrict__ er)
{
    int wid  = (blockIdx.x * 256 + threadIdx.x) >> 6;
    int lane = threadIdx.x & 63;
    if (wid >= NN * H) return;
    int n = wid / H, h = wid % H;
    const float* f = feat + (size_t)n * (H * 128) + h * 128;
    float2 fv = *(const float2*)&f[lane * 2];
    float2 a1 = *(const float2*)&al[h * 128 + lane * 2];
    float2 a2 = *(const float2*)&ar[h * 128 + lane * 2];
    float sl = fv.x * a1.x + fv.y * a1.y;
    float sr = fv.x * a2.x + fv.y * a2.y;
    #pragma unroll
    for (int off = 32; off > 0; off >>= 1) {
        sl += __shfl_down(sl, off);
        sr += __shfl_down(sr, off);
    }
    if (lane == 0) { el[wid] = sl; er[wid] = sr; }
}

// -------- per-edge attention weight w = exp(leakyrelu(el[s]+er[d])) --------
template <int H>
__global__ __launch_bounds__(256) void edge_w_kernel(
    const int* __restrict__ src, const int* __restrict__ dst,
    const float* __restrict__ el, const float* __restrict__ er,
    float* __restrict__ w)
{
    int e = blockIdx.x * 256 + threadIdx.x;
    if (e >= NE) return;
    int s = src[e], d = dst[e];
    if constexpr (H == 4) {
        float4 a = *(const float4*)&el[s * 4];
        float4 b = *(const float4*)&er[d * 4];
        float4 v = make_float4(a.x + b.x, a.y + b.y, a.z + b.z, a.w + b.w);
        v.x = v.x > 0.f ? v.x : 0.2f * v.x;
        v.y = v.y > 0.f ? v.y : 0.2f * v.y;
        v.z = v.z > 0.f ? v.z : 0.2f * v.z;
        v.w = v.w > 0.f ? v.w : 0.2f * v.w;
        *(float4*)&w[e * 4] = make_float4(__expf(v.x), __expf(v.y), __expf(v.z), __expf(v.w));
    } else {
        float v = el[s] + er[d];
        v = v > 0.f ? v : 0.2f * v;
        w[e] = __expf(v);
    }
}

// ---- CSR gather-aggregate: one wave per dst node, registers only, bias folded ----
template <int H>
__global__ __launch_bounds__(256) void agg_kernel(
    const int* __restrict__ row, const int* __restrict__ eidx,
    const int* __restrict__ src, const float* __restrict__ w,
    const float* __restrict__ feat, const float* __restrict__ bias,
    float* __restrict__ out)
{
    int wave = (blockIdx.x * 256 + threadIdx.x) >> 6;
    int lane = threadIdx.x & 63;
    if (wave >= NN) return;
    int r0 = row[wave], r1 = row[wave + 1];

    if constexpr (H == 4) {
        float d0 = 0.f, d1 = 0.f, d2 = 0.f, d3 = 0.f;
        for (int i = r0 + lane; i < r1; i += 64) {
            float4 wv = *(const float4*)&w[eidx[i] * 4];
            d0 += wv.x; d1 += wv.y; d2 += wv.z; d3 += wv.w;
        }
        #pragma unroll
        for (int off = 32; off > 0; off >>= 1) {
            d0 += __shfl_xor(d0, off);
            d1 += __shfl_xor(d1, off);
            d2 += __shfl_xor(d2, off);
            d3 += __shfl_xor(d3, off);
        }
        float4 a0 = {0.f,0.f,0.f,0.f}, a1 = {0.f,0.f,0.f,0.f};
        for (int i = r0; i < r1; ++i) {
            int e = eidx[i];
            int s = src[e];
            float4 wv = *(const float4*)&w[e * 4];
            const float* f = feat + (size_t)s * 512;
            float4 v0 = *(const float4*)&f[lane * 4];
            float4 v1 = *(const float4*)&f[256 + lane * 4];
            float alo = (lane & 32) ? wv.y : wv.x;
            float ahi = (lane & 32) ? wv.w : wv.z;
            a0.x = fmaf(v0.x, alo, a0.x); a0.y = fmaf(v0.y, alo, a0.y);
            a0.z = fmaf(v0.z, alo, a0.z); a0.w = fmaf(v0.w, alo, a0.w);
            a1.x = fmaf(v1.x, ahi, a1.x); a1.y = fmaf(v1.y, ahi, a1.y);
            a1.z = fmaf(v1.z, ahi, a1.z); a1.w = fmaf(v1.w, ahi, a1.w);
        }
        float ilo = (lane & 32) ? d1 : d0;
        float ihi = (lane & 32) ? d3 : d2;
        ilo = (r1 > r0) ? 1.0f / ilo : 0.0f;
        ihi = (r1 > r0) ? 1.0f / ihi : 0.0f;
        float4 b0 = *(const float4*)&bias[lane * 4];
        float4 b1v = *(const float4*)&bias[256 + lane * 4];
        float* o = out + (size_t)wave * 512;
        *(float4*)&o[lane * 4] = make_float4(
            fmaf(a0.x, ilo, b0.x), fmaf(a0.y, ilo, b0.y),
            fmaf(a0.z, ilo, b0.z), fmaf(a0.w, ilo, b0.w));
        *(float4*)&o[256 + lane * 4] = make_float4(
            fmaf(a1.x, ihi, b1v.x), fmaf(a1.y, ihi, b1v.y),
            fmaf(a1.z, ihi, b1v.z), fmaf(a1.w, ihi, b1v.w));
    } else {
        float den = 0.f;
        for (int i = r0 + lane; i < r1; i += 64) den += w[eidx[i]];
        #pragma unroll
        for (int off = 32; off > 0; off >>= 1) den += __shfl_xor(den, off);
        float2 a = {0.f, 0.f};
        for (int i = r0; i < r1; ++i) {
            int e = eidx[i];
            int s = src[e];
            float wv = w[e];
            float2 v = *(const float2*)&feat[(size_t)s * 128 + lane * 2];
            a.x = fmaf(v.x, wv, a.x);
            a.y = fmaf(v.y, wv, a.y);
        }
        float inv = (r1 > r0) ? 1.0f / den : 0.0f;
        float2 b = *(const float2*)&bias[lane * 2];
        float* o = out + (size_t)wave * 128;
        *(float2*)&o[lane * 2] = make_float2(fmaf(a.x, inv, b.x), fmaf(a.y, inv, b.y));
    }
}

// --------- per-graph mean via binary search on sorted graph_ids ---------
__global__ __launch_bounds__(128) void graph_mean_kernel(
    const int* __restrict__ gid, const float* __restrict__ h2, float* __restrict__ hg)
{
    int g = blockIdx.x;
    int t = threadIdx.x;
    int lo = 0, hi = NN;
    while (lo < hi) { int m = (lo + hi) >> 1; if (gid[m] < g) lo = m + 1; else hi = m; }
    int start = lo;
    lo = start; hi = NN;
    while (lo < hi) { int m = (lo + hi) >> 1; if (gid[m] < g + 1) lo = m + 1; else hi = m; }
    int end = lo;
    float acc = 0.f;
    for (int n = start; n < end; ++n) acc += h2[(size_t)n * 128 + t];
    float c = fmaxf((float)(end - start), 1.0f);
    hg[g * 128 + t] = acc / c;
}

// --------- node MLP: out = relu(h @ W1 + b1) @ W2 + b2 (one node/block) ---------
__global__ __launch_bounds__(128) void node_mlp_kernel(
    const float* __restrict__ h, const float* __restrict__ W1,
    const float* __restrict__ b1, const float* __restrict__ W2,
    const float* __restrict__ b2, float* __restrict__ out)
{
    __shared__ float row[128];
    __shared__ float hid[128];
    int n = blockIdx.x;
    int t = threadIdx.x;
    row[t] = h[(size_t)n * 128 + t];
    __syncthreads();
    float acc = b1[t];
    #pragma unroll 8
    for (int k = 0; k < 128; ++k) acc = fmaf(row[k], W1[k * 128 + t], acc);
    hid[t] = fmaxf(acc, 0.f);
    __syncthreads();
    if (t < 2) {
        float o = b2[t];
        for (int k = 0; k < 128; ++k) o = fmaf(hid[k], W2[k * 2 + t], o);
        out[(size_t)n * 2 + t] = o;
    }
}

__global__ __launch_bounds__(128) void graph_mlp_kernel(
    const float* __restrict__ hg,
    const float* __restrict__ W1, const float* __restrict__ b1,
    const float* __restrict__ W2, const float* __restrict__ b2,
    float* __restrict__ out)
{
    __shared__ float row[128];
    __shared__ float hid[128];
    int g = blockIdx.x;
    int t = threadIdx.x;
    row[t] = hg[(size_t)g * 128 + t];
    __syncthreads();
    float acc = b1[t];
    #pragma unroll 8
    for (int k = 0; k < 128; ++k) acc = fmaf(row[k], W1[k * 128 + t], acc);
    hid[t] = fmaxf(acc, 0.f);
    __syncthreads();
    if (t < 2) {
        float o = b2[t];
        for (int k = 0; k < 128; ++k) o = fmaf(hid[k], W2[k * 2 + t], o);
        out[(size_t)g * 2 + t] = o;
    }
}

// ---------------------------------------------------------------------------
// workspace layout (float offsets)
static constexpr size_t O_FEAT1 = 0;          // 40000*512 (layer2: feat2 @0, h2 @5120000)
static constexpr size_t O_H1    = 20480000;   // 40000*512
static constexpr size_t O_H2    = 5120000;    // alias inside feat1 region
static constexpr size_t O_B2T   = 10240000;   // inside feat1 region, live only for layer 2
static constexpr size_t O_EW    = 40960000;   // per-layer attn scratch (1.92M floats)
static constexpr size_t O_HG    = 42880000;   // 16384
static constexpr size_t O_INT   = 42896384;   // int region start
// int offsets within O_INT:
static constexpr size_t I_ROW  = 0;        // 40001
static constexpr size_t I_BSUM = 40064;    // 160
static constexpr size_t I_CNT  = 40224;    // 40000
static constexpr size_t I_FILL = 80224;    // 40000
static constexpr size_t I_EIDX = 120224;   // 400000

extern "C" void kernel_launch(void* const* d_in, const int* in_sizes, int n_in,
                              void* d_out, int out_size, void* d_ws, size_t ws_size,
                              hipStream_t stream)
{
    const float* x    = (const float*)d_in[0];
    const int*   src  = (const int*)d_in[1];
    const int*   dst  = (const int*)d_in[2];
    const int*   gid  = (const int*)d_in[3];
    const float* W1   = (const float*)d_in[4];
    const float* al1  = (const float*)d_in[5];
    const float* ar1  = (const float*)d_in[6];
    const float* b1   = (const float*)d_in[7];
    const float* W2   = (const float*)d_in[8];
    const float* al2  = (const float*)d_in[9];
    const float* ar2  = (const float*)d_in[10];
    const float* b2   = (const float*)d_in[11];
    const float* nW1  = (const float*)d_in[12];
    const float* nb1  = (const float*)d_in[13];
    const float* nW2  = (const float*)d_in[14];
    const float* nb2  = (const float*)d_in[15];
    const float* gW1  = (const float*)d_in[16];
    const float* gb1  = (const float*)d_in[17];
    const float* gW2  = (const float*)d_in[18];
    const float* gb2  = (const float*)d_in[19];
    float* out = (float*)d_out;
    float* ws  = (float*)d_ws;

    float* feat1 = ws + O_FEAT1;
    float* h1    = ws + O_H1;
    float* feat2 = ws + O_FEAT1;   // alias (feat1 dead after agg<4>)
    float* h2    = ws + O_H2;
    float* el1   = ws + O_EW;
    float* er1   = ws + O_EW + 160000;
    float* w1e   = ws + O_EW + 320000;
    float* el2   = ws + O_EW;      // alias (layer-1 attn scratch dead)
    float* er2   = ws + O_EW + 40000;
    float* w2e   = ws + O_EW + 80000;
    float* hg    = ws + O_HG;
    int*   ibase = (int*)(ws + O_INT);
    int*   row   = ibase + I_ROW;
    int*   bsum  = ibase + I_BSUM;
    int*   cnt   = ibase + I_CNT;
    int*   fill  = ibase + I_FILL;
    int*   eidx  = ibase + I_EIDX;

    // split-bf16 copies of W1/W2 (transposed to [N][K]):
    // B1t lives in h1's region (h1 not written until agg<4>, by which time B1t is dead).
    unsigned short* B1h = (unsigned short*)(ws + O_H1);
    unsigned short* B1l = B1h + 512 * 768;
    // B2t lives in feat1's dead zone (feat2/h2 use only the first 10.24M floats).
    unsigned short* B2h = (unsigned short*)(ws + O_B2T);
    unsigned short* B2l = B2h + 128 * 512;

    // ---- CSR build (depends only on dst) ----
    hipMemsetAsync(cnt, 0, NN * sizeof(int), stream);
    hist_kernel<<<(NE + 255) / 256, 256, 0, stream>>>(dst, cnt);
    scanA_kernel<<<NB_SCAN, 256, 0, stream>>>(cnt, row, bsum);
    scanB_kernel<<<1, 256, 0, stream>>>(bsum);
    scanC_kernel<<<NB_SCAN, 256, 0, stream>>>(row, bsum, fill);
    permute_kernel<<<(NE + 255) / 256, 256, 0, stream>>>(dst, fill, eidx);

    // ---- GAT layer 1 (768 -> 4x128) ----
    conv_bt<<<(512 * 768 + 255) / 256, 256, 0, stream>>>(W1, B1h, B1l, 768, 512);
    gemm_split<<<dim3(313, 4), 256, 0, stream>>>(x, B1h, B1l, feat1, NN, 768, 512);
    eler_kernel<4><<<(NN * 4 * 64 + 255) / 256, 256, 0, stream>>>(feat1, al1, ar1, el1, er1);
    edge_w_kernel<4><<<(NE + 255) / 256, 256, 0, stream>>>(src, dst, el1, er1, w1e);
    agg_kernel<4><<<10000, 256, 0, stream>>>(row, eidx, src, w1e, feat1, b1, h1);

    // ---- GAT layer 2 (512 -> 1x128) ----
    conv_bt<<<(128 * 512 + 255) / 256, 256, 0, stream>>>(W2, B2h, B2l, 512, 128);
    gemm_split<<<dim3(313, 1), 256, 0, stream>>>(h1, B2h, B2l, feat2, NN, 512, 128);
    eler_kernel<1><<<(NN * 64 + 255) / 256, 256, 0, stream>>>(feat2, al2, ar2, el2, er2);
    edge_w_kernel<1><<<(NE + 255) / 256, 256, 0, stream>>>(src, dst, el2, er2, w2e);
    agg_kernel<1><<<10000, 256, 0, stream>>>(row, eidx, src, w2e, feat2, b2, h2);

    // ---- pooling + MLPs ----
    graph_mean_kernel<<<NG, 128, 0, stream>>>(gid, h2, hg);
    node_mlp_kernel<<<NN, 128, 0, stream>>>(h2, nW1, nb1, nW2, nb2, out);
    graph_mlp_kernel<<<NG, 128, 0, stream>>>(hg, gW1, gb1, gW2, gb2, out + (size_t)NN * 2);
}

// Round 9
// 940.787 us; speedup vs baseline: 4.3429x; 1.0625x over previous
//
#include <hip/hip_runtime.h>
#include <cstddef>

#define NN 40000
#define NE 400000
#define NG 128
#define NB_SCAN 157  // ceil(40000/256)

typedef __attribute__((ext_vector_type(8))) short bf16x8;
typedef __attribute__((ext_vector_type(4))) float f32x4;

// split fp32 x ~= hi + lo, both bf16 (RNE). |x - hi - lo| ~ 2^-17 |x|
__device__ __forceinline__ void split1(float x, unsigned short& h, unsigned short& l)
{
    unsigned u = __float_as_uint(x);
    unsigned rh = u + 0x7FFFu + ((u >> 16) & 1u);
    h = (unsigned short)(rh >> 16);
    float fh = __uint_as_float(((unsigned)h) << 16);
    float r = x - fh;
    unsigned u2 = __float_as_uint(r);
    unsigned rl = u2 + 0x7FFFu + ((u2 >> 16) & 1u);
    l = (unsigned short)(rl >> 16);
}

// ---- B[K][N] fp32 -> Bt hi/lo [N][K] bf16 (tiny, once per layer) ----
__global__ void conv_bt(const float* __restrict__ B, unsigned short* __restrict__ hi,
                        unsigned short* __restrict__ lo, int K, int N)
{
    int e = blockIdx.x * 256 + threadIdx.x;
    if (e >= K * N) return;
    int n = e / K, k = e - n * K;
    unsigned short h, l;
    split1(B[(size_t)k * N + n], h, l);
    hi[e] = h; lo[e] = l;
}

// ---------- split-bf16 MFMA GEMM: C[M,N] = A[M,K] @ B[K,N] (fp32 io) ----------
// 128x128 tile, BK=32, 4 waves (2x2 of 64x64), 16x16x32 bf16 MFMA, 3-product split.
// swz=1 (layer 1, 313x4 tiles): blockIdx mapped so the 4 bn-siblings of a bm
// land on the SAME XCD (round-robin model: consecutive blockIdx -> different XCD,
// ids 8 apart -> same XCD). Each A row then hits one XCD's L2 exactly once.
#define LDK 40  // padded k-stride (bf16 elems): 80B rows, 16B-aligned b128 frags

__global__ __launch_bounds__(256) void gemm_split(
    const float* __restrict__ A, const unsigned short* __restrict__ Bh,
    const unsigned short* __restrict__ Bl, float* __restrict__ C,
    int M, int K, int N, int swz)
{
    __shared__ unsigned short Ah_s[128 * LDK];
    __shared__ unsigned short Al_s[128 * LDK];
    __shared__ unsigned short Bh_s[128 * LDK];
    __shared__ unsigned short Bl_s[128 * LDK];

    int bm, bn;
    if (swz) {
        // grid = 8 xcd * 40 bm_local * 4 bn = 1280 blocks (28 idle)
        int xcd = blockIdx.x & 7;
        int loc = blockIdx.x >> 3;
        int bmi = xcd * 40 + (loc >> 2);
        if (bmi >= 313) return;
        bm = bmi * 128;
        bn = (loc & 3) * 128;
    } else {
        bm = blockIdx.x * 128;
        bn = blockIdx.y * 128;
    }

    const int t    = threadIdx.x;
    const int lane = t & 63;
    const int wid  = t >> 6;
    const int wr   = wid >> 1, wc = wid & 1;

    const int sr = t >> 1;         // 0..127: tile row (A) / tile col (B)
    const int sk = (t & 1) * 16;   // 0 or 16: k-offset

    const int arow = bm + sr;
    const bool aval = (arow < M);
    const float* Ap = A + (size_t)arow * K + sk;
    const unsigned short* Bhp = Bh + (size_t)(bn + sr) * K + sk;
    const unsigned short* Blp = Bl + (size_t)(bn + sr) * K + sk;

    f32x4 acc[4][4];
    #pragma unroll
    for (int i = 0; i < 4; ++i)
        #pragma unroll
        for (int j = 0; j < 4; ++j) acc[i][j] = (f32x4){0.f, 0.f, 0.f, 0.f};

    float4 abuf[4];
    uint4 bhbuf[2], blbuf[2];
    const int NT = K / 32;

    auto load_tile = [&](int kt) {
        const int kb = kt * 32;
        if (aval) {
            #pragma unroll
            for (int q = 0; q < 4; ++q) abuf[q] = *(const float4*)(Ap + kb + q * 4);
        } else {
            #pragma unroll
            for (int q = 0; q < 4; ++q) abuf[q] = make_float4(0.f, 0.f, 0.f, 0.f);
        }
        bhbuf[0] = *(const uint4*)(Bhp + kb);
        bhbuf[1] = *(const uint4*)(Bhp + kb + 8);
        blbuf[0] = *(const uint4*)(Blp + kb);
        blbuf[1] = *(const uint4*)(Blp + kb + 8);
    };

    auto store_tile = [&]() {
        unsigned short h[16], l[16];
        #pragma unroll
        for (int q = 0; q < 4; ++q) {
            split1(abuf[q].x, h[q * 4 + 0], l[q * 4 + 0]);
            split1(abuf[q].y, h[q * 4 + 1], l[q * 4 + 1]);
            split1(abuf[q].z, h[q * 4 + 2], l[q * 4 + 2]);
            split1(abuf[q].w, h[q * 4 + 3], l[q * 4 + 3]);
        }
        *(uint4*)&Ah_s[sr * LDK + sk]     = *(uint4*)&h[0];
        *(uint4*)&Ah_s[sr * LDK + sk + 8] = *(uint4*)&h[8];
        *(uint4*)&Al_s[sr * LDK + sk]     = *(uint4*)&l[0];
        *(uint4*)&Al_s[sr * LDK + sk + 8] = *(uint4*)&l[8];
        *(uint4*)&Bh_s[sr * LDK + sk]     = bhbuf[0];
        *(uint4*)&Bh_s[sr * LDK + sk + 8] = bhbuf[1];
        *(uint4*)&Bl_s[sr * LDK + sk]     = blbuf[0];
        *(uint4*)&Bl_s[sr * LDK + sk + 8] = blbuf[1];
    };

    auto compute = [&]() {
        const int fr = lane & 15;
        const int fk = (lane >> 4) * 8;
        bf16x8 bhf[4], blf[4];
        #pragma unroll
        for (int ni = 0; ni < 4; ++ni) {
            bhf[ni] = *(bf16x8*)&Bh_s[(wc * 64 + ni * 16 + fr) * LDK + fk];
            blf[ni] = *(bf16x8*)&Bl_s[(wc * 64 + ni * 16 + fr) * LDK + fk];
        }
        #pragma unroll
        for (int mi = 0; mi < 4; ++mi) {
            bf16x8 ah = *(bf16x8*)&Ah_s[(wr * 64 + mi * 16 + fr) * LDK + fk];
            bf16x8 al = *(bf16x8*)&Al_s[(wr * 64 + mi * 16 + fr) * LDK + fk];
            #pragma unroll
            for (int ni = 0; ni < 4; ++ni) {
                acc[mi][ni] = __builtin_amdgcn_mfma_f32_16x16x32_bf16(ah, bhf[ni], acc[mi][ni], 0, 0, 0);
                acc[mi][ni] = __builtin_amdgcn_mfma_f32_16x16x32_bf16(ah, blf[ni], acc[mi][ni], 0, 0, 0);
                acc[mi][ni] = __builtin_amdgcn_mfma_f32_16x16x32_bf16(al, bhf[ni], acc[mi][ni], 0, 0, 0);
            }
        }
    };

    load_tile(0);
    store_tile();
    __syncthreads();
    for (int kt = 0;;) {
        if (kt + 1 < NT) load_tile(kt + 1);  // global->reg prefetch overlaps MFMA
        compute();
        ++kt;
        if (kt == NT) break;
        __syncthreads();   // all waves done reading LDS
        store_tile();
        __syncthreads();   // next tile ready
    }

    // C/D layout (m89): col = lane&15, row = (lane>>4)*4 + reg
    const int fr = lane & 15;
    const int fq = lane >> 4;
    #pragma unroll
    for (int mi = 0; mi < 4; ++mi) {
        int r0 = bm + wr * 64 + mi * 16 + fq * 4;
        #pragma unroll
        for (int ni = 0; ni < 4; ++ni) {
            int c = bn + wc * 64 + ni * 16 + fr;
            #pragma unroll
            for (int q = 0; q < 4; ++q) {
                int r = r0 + q;
                if (r < M) C[(size_t)r * N + c] = acc[mi][ni][q];
            }
        }
    }
}

// ---------------- CSR build: histogram -> scan -> permute ----------------
__global__ void hist_kernel(const int* __restrict__ dst, int* __restrict__ cnt)
{
    int e = blockIdx.x * 256 + threadIdx.x;
    if (e < NE) atomicAdd(&cnt[dst[e]], 1);
}

__global__ __launch_bounds__(256) void scanA_kernel(
    const int* __restrict__ cnt, int* __restrict__ row, int* __restrict__ bsum)
{
    __shared__ int s[256];
    int t = threadIdx.x;
    int i = blockIdx.x * 256 + t;
    int v = (i < NN) ? cnt[i] : 0;
    s[t] = v;
    __syncthreads();
    #pragma unroll
    for (int off = 1; off < 256; off <<= 1) {
        int x = (t >= off) ? s[t - off] : 0;
        __syncthreads();
        s[t] += x;
        __syncthreads();
    }
    if (i < NN) row[i] = s[t] - v;     // exclusive
    if (t == 255) bsum[blockIdx.x] = s[255];
}

__global__ __launch_bounds__(256) void scanB_kernel(int* __restrict__ bsum)
{
    __shared__ int s[256];
    int t = threadIdx.x;
    int v = (t < NB_SCAN) ? bsum[t] : 0;
    s[t] = v;
    __syncthreads();
    #pragma unroll
    for (int off = 1; off < 256; off <<= 1) {
        int x = (t >= off) ? s[t - off] : 0;
        __syncthreads();
        s[t] += x;
        __syncthreads();
    }
    if (t < NB_SCAN) bsum[t] = s[t] - v;  // exclusive
}

__global__ void scanC_kernel(int* __restrict__ row, const int* __restrict__ bsum,
                             int* __restrict__ fill)
{
    int i = blockIdx.x * 256 + threadIdx.x;
    if (i < NN) {
        int r = row[i] + bsum[blockIdx.x];
        row[i] = r;
        fill[i] = r;
    }
    if (i == 0) row[NN] = NE;
}

__global__ void permute_kernel(const int* __restrict__ dst, int* __restrict__ fill,
                               int* __restrict__ eidx)
{
    int e = blockIdx.x * 256 + threadIdx.x;
    if (e < NE) {
        int pos = atomicAdd(&fill[dst[e]], 1);
        eidx[pos] = e;
    }
}

// ------------- el/er: per (node, head) dot(feat[n,h,:], a[h,:]) -------------
template <int H>
__global__ __launch_bounds__(256) void eler_kernel(
    const float* __restrict__ feat, const float* __restrict__ al,
    const float* __restrict__ ar, float* __restrict__ el, float* __restrict__ er)
{
    int wid  = (blockIdx.x * 256 + threadIdx.x) >> 6;
    int lane = threadIdx.x & 63;
    if (wid >= NN * H) return;
    int n = wid / H, h = wid % H;
    const float* f = feat + (size_t)n * (H * 128) + h * 128;
    float2 fv = *(const float2*)&f[lane * 2];
    float2 a1 = *(const float2*)&al[h * 128 + lane * 2];
    float2 a2 = *(const float2*)&ar[h * 128 + lane * 2];
    float sl = fv.x * a1.x + fv.y * a1.y;
    float sr = fv.x * a2.x + fv.y * a2.y;
    #pragma unroll
    for (int off = 32; off > 0; off >>= 1) {
        sl += __shfl_down(sl, off);
        sr += __shfl_down(sr, off);
    }
    if (lane == 0) { el[wid] = sl; er[wid] = sr; }
}

// -------- per-edge attention weight w = exp(leakyrelu(el[s]+er[d])) --------
template <int H>
__global__ __launch_bounds__(256) void edge_w_kernel(
    const int* __restrict__ src, const int* __restrict__ dst,
    const float* __restrict__ el, const float* __restrict__ er,
    float* __restrict__ w)
{
    int e = blockIdx.x * 256 + threadIdx.x;
    if (e >= NE) return;
    int s = src[e], d = dst[e];
    if constexpr (H == 4) {
        float4 a = *(const float4*)&el[s * 4];
        float4 b = *(const float4*)&er[d * 4];
        float4 v = make_float4(a.x + b.x, a.y + b.y, a.z + b.z, a.w + b.w);
        v.x = v.x > 0.f ? v.x : 0.2f * v.x;
        v.y = v.y > 0.f ? v.y : 0.2f * v.y;
        v.z = v.z > 0.f ? v.z : 0.2f * v.z;
        v.w = v.w > 0.f ? v.w : 0.2f * v.w;
        *(float4*)&w[e * 4] = make_float4(__expf(v.x), __expf(v.y), __expf(v.z), __expf(v.w));
    } else {
        float v = el[s] + er[d];
        v = v > 0.f ? v : 0.2f * v;
        w[e] = __expf(v);
    }
}

// ---- CSR gather-aggregate, latency-optimized: one wave per dst node.
// Cooperative metadata load: lane j loads eidx/src/w for edge j (3 serial loads
// per 64 edges instead of per edge), broadcast via shfl; 2-edge-unrolled gather.
template <int H>
__global__ __launch_bounds__(256) void agg_kernel(
    const int* __restrict__ row, const int* __restrict__ eidx,
    const int* __restrict__ src, const float* __restrict__ w,
    const float* __restrict__ feat, const float* __restrict__ bias,
    float* __restrict__ out)
{
    int wave = (blockIdx.x * 256 + threadIdx.x) >> 6;
    int lane = threadIdx.x & 63;
    if (wave >= NN) return;
    int r0 = row[wave], r1 = row[wave + 1];
    int nedge = r1 - r0;

    if constexpr (H == 4) {
        float d0 = 0.f, d1 = 0.f, d2 = 0.f, d3 = 0.f;
        float4 a0 = {0.f,0.f,0.f,0.f}, a1 = {0.f,0.f,0.f,0.f};
        for (int base = 0; base < nedge; base += 64) {
            int cnt = nedge - base; if (cnt > 64) cnt = 64;
            int s = 0;
            float4 wv = {0.f,0.f,0.f,0.f};
            if (lane < cnt) {
                int e = eidx[r0 + base + lane];
                s = src[e];
                wv = *(const float4*)&w[e * 4];
            }
            d0 += wv.x; d1 += wv.y; d2 += wv.z; d3 += wv.w;
            int j = 0;
            for (; j + 1 < cnt; j += 2) {
                int s0 = __shfl(s, j), s1 = __shfl(s, j + 1);
                float wx0 = __shfl(wv.x, j), wy0 = __shfl(wv.y, j);
                float wz0 = __shfl(wv.z, j), ww0 = __shfl(wv.w, j);
                float wx1 = __shfl(wv.x, j + 1), wy1 = __shfl(wv.y, j + 1);
                float wz1 = __shfl(wv.z, j + 1), ww1 = __shfl(wv.w, j + 1);
                const float* f0 = feat + (size_t)s0 * 512;
                const float* f1 = feat + (size_t)s1 * 512;
                float4 p00 = *(const float4*)&f0[lane * 4];
                float4 p01 = *(const float4*)&f0[256 + lane * 4];
                float4 p10 = *(const float4*)&f1[lane * 4];
                float4 p11 = *(const float4*)&f1[256 + lane * 4];
                float alo0 = (lane & 32) ? wy0 : wx0, ahi0 = (lane & 32) ? ww0 : wz0;
                float alo1 = (lane & 32) ? wy1 : wx1, ahi1 = (lane & 32) ? ww1 : wz1;
                a0.x = fmaf(p00.x, alo0, a0.x); a0.y = fmaf(p00.y, alo0, a0.y);
                a0.z = fmaf(p00.z, alo0, a0.z); a0.w = fmaf(p00.w, alo0, a0.w);
                a1.x = fmaf(p01.x, ahi0, a1.x); a1.y = fmaf(p01.y, ahi0, a1.y);
                a1.z = fmaf(p01.z, ahi0, a1.z); a1.w = fmaf(p01.w, ahi0, a1.w);
                a0.x = fmaf(p10.x, alo1, a0.x); a0.y = fmaf(p10.y, alo1, a0.y);
                a0.z = fmaf(p10.z, alo1, a0.z); a0.w = fmaf(p10.w, alo1, a0.w);
                a1.x = fmaf(p11.x, ahi1, a1.x); a1.y = fmaf(p11.y, ahi1, a1.y);
                a1.z = fmaf(p11.z, ahi1, a1.z); a1.w = fmaf(p11.w, ahi1, a1.w);
            }
            if (j < cnt) {
                int s0 = __shfl(s, j);
                float wx0 = __shfl(wv.x, j), wy0 = __shfl(wv.y, j);
                float wz0 = __shfl(wv.z, j), ww0 = __shfl(wv.w, j);
                const float* f0 = feat + (size_t)s0 * 512;
                float4 p00 = *(const float4*)&f0[lane * 4];
                float4 p01 = *(const float4*)&f0[256 + lane * 4];
                float alo0 = (lane & 32) ? wy0 : wx0, ahi0 = (lane & 32) ? ww0 : wz0;
                a0.x = fmaf(p00.x, alo0, a0.x); a0.y = fmaf(p00.y, alo0, a0.y);
                a0.z = fmaf(p00.z, alo0, a0.z); a0.w = fmaf(p00.w, alo0, a0.w);
                a1.x = fmaf(p01.x, ahi0, a1.x); a1.y = fmaf(p01.y, ahi0, a1.y);
                a1.z = fmaf(p01.z, ahi0, a1.z); a1.w = fmaf(p01.w, ahi0, a1.w);
            }
        }
        #pragma unroll
        for (int off = 32; off > 0; off >>= 1) {
            d0 += __shfl_xor(d0, off);
            d1 += __shfl_xor(d1, off);
            d2 += __shfl_xor(d2, off);
            d3 += __shfl_xor(d3, off);
        }
        float ilo = (lane & 32) ? d1 : d0;
        float ihi = (lane & 32) ? d3 : d2;
        ilo = (nedge > 0) ? 1.0f / ilo : 0.0f;
        ihi = (nedge > 0) ? 1.0f / ihi : 0.0f;
        float4 b0 = *(const float4*)&bias[lane * 4];
        float4 b1v = *(const float4*)&bias[256 + lane * 4];
        float* o = out + (size_t)wave * 512;
        *(float4*)&o[lane * 4] = make_float4(
            fmaf(a0.x, ilo, b0.x), fmaf(a0.y, ilo, b0.y),
            fmaf(a0.z, ilo, b0.z), fmaf(a0.w, ilo, b0.w));
        *(float4*)&o[256 + lane * 4] = make_float4(
            fmaf(a1.x, ihi, b1v.x), fmaf(a1.y, ihi, b1v.y),
            fmaf(a1.z, ihi, b1v.z), fmaf(a1.w, ihi, b1v.w));
    } else {
        float den = 0.f;
        float2 a = {0.f, 0.f};
        for (int base = 0; base < nedge; base += 64) {
            int cnt = nedge - base; if (cnt > 64) cnt = 64;
            int s = 0;
            float wv = 0.f;
            if (lane < cnt) {
                int e = eidx[r0 + base + lane];
                s = src[e];
                wv = w[e];
            }
            den += wv;
            int j = 0;
            for (; j + 1 < cnt; j += 2) {
                int s0 = __shfl(s, j), s1 = __shfl(s, j + 1);
                float w0 = __shfl(wv, j), w1 = __shfl(wv, j + 1);
                float2 p0 = *(const float2*)&feat[(size_t)s0 * 128 + lane * 2];
                float2 p1 = *(const float2*)&feat[(size_t)s1 * 128 + lane * 2];
                a.x = fmaf(p0.x, w0, a.x); a.y = fmaf(p0.y, w0, a.y);
                a.x = fmaf(p1.x, w1, a.x); a.y = fmaf(p1.y, w1, a.y);
            }
            if (j < cnt) {
                int s0 = __shfl(s, j);
                float w0 = __shfl(wv, j);
                float2 p0 = *(const float2*)&feat[(size_t)s0 * 128 + lane * 2];
                a.x = fmaf(p0.x, w0, a.x); a.y = fmaf(p0.y, w0, a.y);
            }
        }
        #pragma unroll
        for (int off = 32; off > 0; off >>= 1) den += __shfl_xor(den, off);
        float inv = (nedge > 0) ? 1.0f / den : 0.0f;
        float2 b = *(const float2*)&bias[lane * 2];
        float* o = out + (size_t)wave * 128;
        *(float2*)&o[lane * 2] = make_float2(fmaf(a.x, inv, b.x), fmaf(a.y, inv, b.y));
    }
}

// --------- per-graph mean via binary search on sorted graph_ids ---------
__global__ __launch_bounds__(128) void graph_mean_kernel(
    const int* __restrict__ gid, const float* __restrict__ h2, float* __restrict__ hg)
{
    int g = blockIdx.x;
    int t = threadIdx.x;
    int lo = 0, hi = NN;
    while (lo < hi) { int m = (lo + hi) >> 1; if (gid[m] < g) lo = m + 1; else hi = m; }
    int start = lo;
    lo = start; hi = NN;
    while (lo < hi) { int m = (lo + hi) >> 1; if (gid[m] < g + 1) lo = m + 1; else hi = m; }
    int end = lo;
    float acc = 0.f;
    for (int n = start; n < end; ++n) acc += h2[(size_t)n * 128 + t];
    float c = fmaxf((float)(end - start), 1.0f);
    hg[g * 128 + t] = acc / c;
}

// --------- node MLP: out = relu(h @ W1 + b1) @ W2 + b2 (one node/block) ---------
__global__ __launch_bounds__(128) void node_mlp_kernel(
    const float* __restrict__ h, const float* __restrict__ W1,
    const float* __restrict__ b1, const float* __restrict__ W2,
    const float* __restrict__ b2, float* __restrict__ out)
{
    __shared__ float row[128];
    __shared__ float hid[128];
    int n = blockIdx.x;
    int t = threadIdx.x;
    row[t] = h[(size_t)n * 128 + t];
    __syncthreads();
    float acc = b1[t];
    #pragma unroll 8
    for (int k = 0; k < 128; ++k) acc = fmaf(row[k], W1[k * 128 + t], acc);
    hid[t] = fmaxf(acc, 0.f);
    __syncthreads();
    if (t < 2) {
        float o = b2[t];
        for (int k = 0; k < 128; ++k) o = fmaf(hid[k], W2[k * 2 + t], o);
        out[(size_t)n * 2 + t] = o;
    }
}

__global__ __launch_bounds__(128) void graph_mlp_kernel(
    const float* __restrict__ hg,
    const float* __restrict__ W1, const float* __restrict__ b1,
    const float* __restrict__ W2, const float* __restrict__ b2,
    float* __restrict__ out)
{
    __shared__ float row[128];
    __shared__ float hid[128];
    int g = blockIdx.x;
    int t = threadIdx.x;
    row[t] = hg[(size_t)g * 128 + t];
    __syncthreads();
    float acc = b1[t];
    #pragma unroll 8
    for (int k = 0; k < 128; ++k) acc = fmaf(row[k], W1[k * 128 + t], acc);
    hid[t] = fmaxf(acc, 0.f);
    __syncthreads();
    if (t < 2) {
        float o = b2[t];
        for (int k = 0; k < 128; ++k) o = fmaf(hid[k], W2[k * 2 + t], o);
        out[(size_t)g * 2 + t] = o;
    }
}

// ---------------------------------------------------------------------------
// workspace layout (float offsets)
static constexpr size_t O_FEAT1 = 0;          // 40000*512 (layer2: feat2 @0, h2 @5120000)
static constexpr size_t O_H1    = 20480000;   // 40000*512
static constexpr size_t O_H2    = 5120000;    // alias inside feat1 region
static constexpr size_t O_B2T   = 10240000;   // inside feat1 region, live only for layer 2
static constexpr size_t O_EW    = 40960000;   // per-layer attn scratch (1.92M floats)
static constexpr size_t O_HG    = 42880000;   // 16384
static constexpr size_t O_INT   = 42896384;   // int region start
// int offsets within O_INT:
static constexpr size_t I_ROW  = 0;        // 40001
static constexpr size_t I_BSUM = 40064;    // 160
static constexpr size_t I_CNT  = 40224;    // 40000
static constexpr size_t I_FILL = 80224;    // 40000
static constexpr size_t I_EIDX = 120224;   // 400000

extern "C" void kernel_launch(void* const* d_in, const int* in_sizes, int n_in,
                              void* d_out, int out_size, void* d_ws, size_t ws_size,
                              hipStream_t stream)
{
    const float* x    = (const float*)d_in[0];
    const int*   src  = (const int*)d_in[1];
    const int*   dst  = (const int*)d_in[2];
    const int*   gid  = (const int*)d_in[3];
    const float* W1   = (const float*)d_in[4];
    const float* al1  = (const float*)d_in[5];
    const float* ar1  = (const float*)d_in[6];
    const float* b1   = (const float*)d_in[7];
    const float* W2   = (const float*)d_in[8];
    const float* al2  = (const float*)d_in[9];
    const float* ar2  = (const float*)d_in[10];
    const float* b2   = (const float*)d_in[11];
    const float* nW1  = (const float*)d_in[12];
    const float* nb1  = (const float*)d_in[13];
    const float* nW2  = (const float*)d_in[14];
    const float* nb2  = (const float*)d_in[15];
    const float* gW1  = (const float*)d_in[16];
    const float* gb1  = (const float*)d_in[17];
    const float* gW2  = (const float*)d_in[18];
    const float* gb2  = (const float*)d_in[19];
    float* out = (float*)d_out;
    float* ws  = (float*)d_ws;

    float* feat1 = ws + O_FEAT1;
    float* h1    = ws + O_H1;
    float* feat2 = ws + O_FEAT1;   // alias (feat1 dead after agg<4>)
    float* h2    = ws + O_H2;
    float* el1   = ws + O_EW;
    float* er1   = ws + O_EW + 160000;
    float* w1e   = ws + O_EW + 320000;
    float* el2   = ws + O_EW;      // alias (layer-1 attn scratch dead)
    float* er2   = ws + O_EW + 40000;
    float* w2e   = ws + O_EW + 80000;
    float* hg    = ws + O_HG;
    int*   ibase = (int*)(ws + O_INT);
    int*   row   = ibase + I_ROW;
    int*   bsum  = ibase + I_BSUM;
    int*   cnt   = ibase + I_CNT;
    int*   fill  = ibase + I_FILL;
    int*   eidx  = ibase + I_EIDX;

    // split-bf16 copies of W1/W2 (transposed to [N][K]):
    unsigned short* B1h = (unsigned short*)(ws + O_H1);
    unsigned short* B1l = B1h + 512 * 768;
    unsigned short* B2h = (unsigned short*)(ws + O_B2T);
    unsigned short* B2l = B2h + 128 * 512;

    // ---- CSR build (depends only on dst) ----
    hipMemsetAsync(cnt, 0, NN * sizeof(int), stream);
    hist_kernel<<<(NE + 255) / 256, 256, 0, stream>>>(dst, cnt);
    scanA_kernel<<<NB_SCAN, 256, 0, stream>>>(cnt, row, bsum);
    scanB_kernel<<<1, 256, 0, stream>>>(bsum);
    scanC_kernel<<<NB_SCAN, 256, 0, stream>>>(row, bsum, fill);
    permute_kernel<<<(NE + 255) / 256, 256, 0, stream>>>(dst, fill, eidx);

    // ---- GAT layer 1 (768 -> 4x128) ----
    conv_bt<<<(512 * 768 + 255) / 256, 256, 0, stream>>>(W1, B1h, B1l, 768, 512);
    gemm_split<<<1280, 256, 0, stream>>>(x, B1h, B1l, feat1, NN, 768, 512, 1);
    eler_kernel<4><<<(NN * 4 * 64 + 255) / 256, 256, 0, stream>>>(feat1, al1, ar1, el1, er1);
    edge_w_kernel<4><<<(NE + 255) / 256, 256, 0, stream>>>(src, dst, el1, er1, w1e);
    agg_kernel<4><<<10000, 256, 0, stream>>>(row, eidx, src, w1e, feat1, b1, h1);

    // ---- GAT layer 2 (512 -> 1x128) ----
    conv_bt<<<(128 * 512 + 255) / 256, 256, 0, stream>>>(W2, B2h, B2l, 512, 128);
    gemm_split<<<dim3(313, 1), 256, 0, stream>>>(h1, B2h, B2l, feat2, NN, 512, 128, 0);
    eler_kernel<1><<<(NN * 64 + 255) / 256, 256, 0, stream>>>(feat2, al2, ar2, el2, er2);
    edge_w_kernel<1><<<(NE + 255) / 256, 256, 0, stream>>>(src, dst, el2, er2, w2e);
    agg_kernel<1><<<10000, 256, 0, stream>>>(row, eidx, src, w2e, feat2, b2, h2);

    // ---- pooling + MLPs ----
    graph_mean_kernel<<<NG, 128, 0, stream>>>(gid, h2, hg);
    node_mlp_kernel<<<NN, 128, 0, stream>>>(h2, nW1, nb1, nW2, nb2, out);
    graph_mlp_kernel<<<NG, 128, 0, stream>>>(hg, gW1, gb1, gW2, gb2, out + (size_t)NN * 2);
}